// Round 5
// baseline (127.458 us; speedup 1.0000x reference)
//
#include <hip/hip_runtime.h>

#define NBATCH 32
#define DIST 5.0f
#define EPSV 1e-6f
#define INV_SQRT_F 0.17677669529663687f   // 1/sqrt(32)
#define SC_STAGE2 1.72633492e-4f          // 32^{-5/2}
#define GRIDB 256
#define ZPB 254    // blocks 0..253 write z partials; 254: Mk consts; 255: WQD consts

__device__ __forceinline__ float silu_f(float v) { return v / (1.0f + __expf(-v)); }

// monotonic float <-> uint mapping for min/max via integer compares
__device__ __forceinline__ unsigned f2key(float f) {
  unsigned u = __float_as_uint(f);
  return (u & 0x80000000u) ? ~u : (u | 0x80000000u);
}
__device__ __forceinline__ float key2f(unsigned k) {
  return (k & 0x80000000u) ? __uint_as_float(k ^ 0x80000000u) : __uint_as_float(~k);
}

// manual grid barrier: all GRIDB blocks co-resident (2 blocks/CU capacity at 72KB LDS).
// release fence -> arrive -> spin (bounded) -> acquire fence.
__device__ __forceinline__ void gbar(unsigned* ctr, unsigned target) {
  __threadfence();            // agent-scope release of this thread's prior stores
  __syncthreads();
  if (threadIdx.x == 0) {
    atomicAdd(ctr, 1u);       // device-scope by default
    unsigned t = 0;
    while (__hip_atomic_load(ctr, __ATOMIC_ACQUIRE, __HIP_MEMORY_SCOPE_AGENT) < target) {
      __builtin_amdgcn_s_sleep(2);
      if (++t > 4000000u) break;   // safety valve: fail loud (wrong results), never hang
    }
  }
  __syncthreads();
  __threadfence();            // acquire: no stale cache lines for subsequent reads
}

extern "C" __global__ __launch_bounds__(256)
void fused_all(const float* __restrict__ pos, const int* __restrict__ batch,
               const float* __restrict__ xfeat, const float* __restrict__ bw,
               const float* __restrict__ Wqd, const float* __restrict__ Wk1,
               const float* __restrict__ Wk2, const float* __restrict__ Wv1,
               const float* __restrict__ Wv2, const float* __restrict__ Wqg,
               const float* __restrict__ Wkg1, const float* __restrict__ Wkg2,
               const float* __restrict__ Wvg1, const float* __restrict__ Wvg2,
               const float* __restrict__ Wdot, const float* __restrict__ initd,
               float* __restrict__ out_node, float* __restrict__ out_dummy,
               float* ws, int N)
{
  const int blk = blockIdx.x, tid = threadIdx.x;

  // workspace layout (float offsets)
  float*    ws_Tp   = ws;                        // 32*8*512 = 131072 (per-slice T partials)
  float*    ws_denp = ws + 131072;               // 32*8*2 = 512
  float*    ws_zf   = ws + 131584;               // 64
  int*      ws_seg  = (int*)(ws + 131648);       // 33 (+pad to 48)
  float*    ws_Mk   = ws + 131696;               // 256
  float*    ws_WQD  = ws + 131952;               // 1024
  unsigned* ws_zp   = (unsigned*)(ws + 132976);  // ZPB*64 = 16256
  unsigned* ws_ctr  = (unsigned*)(ws + 149232);  // 4 (memset to 0 pre-launch)

  __shared__ unsigned s_pmin[NBATCH], s_pmax[NBATCH];
  __shared__ float s_q[32], s_c[32];
  __shared__ unsigned s_ru[256];
  __shared__ float s_red[256];
  __shared__ float s_bw[8];
  __shared__ float s_Wa[8][8], s_Wb[8][8];
  __shared__ float s_Mk[32][8];
  __shared__ float s_exh[256][16];
  __shared__ float s_xs[256][32];
  __shared__ float s_Tp[4][512];
  __shared__ float s_T[512];
  __shared__ float s_den[2];
  __shared__ float s_dm[2][32];
  __shared__ float s_WQD[32][32];
  __shared__ float s_Bkg[16][32];
  __shared__ float s_Bvg[16][32];
  __shared__ float s_G[32][16];

  if (tid < 8) s_bw[tid] = bw[tid];

  const int ZT = (N + 255) >> 8;

  // ================= phase 0: z partials + segoff + constants =================
  if (blk < ZPB) {
    if (tid < NBATCH) { s_pmin[tid] = 0xFFFFFFFFu; s_pmax[tid] = 0u; }
    __syncthreads();
    for (int t = blk; t < ZT; t += ZPB) {
      int i = (t << 8) + tid;
      if (i < N) {
        int b = batch[i];
        unsigned k = f2key(pos[3 * (size_t)i + 2]);
        atomicMin(&s_pmin[b], k);
        atomicMax(&s_pmax[b], k);
        int bp = (i == 0) ? -1 : batch[i - 1];
        for (int bb = bp + 1; bb <= b; bb++) ws_seg[bb] = i;
        if (i == N - 1) for (int bb = b + 1; bb <= NBATCH; bb++) ws_seg[bb] = N;
      }
    }
    __syncthreads();
    if (tid < NBATCH) {
      ws_zp[blk * 64 + tid]      = s_pmin[tid];
      ws_zp[blk * 64 + 32 + tid] = s_pmax[tid];
    }
  } else if (blk == ZPB) {
    // Mk[f][h] = (1/1024) * sum_g Wk2[h,f*32+g] * c[g],  c = (initd·Wqd·invsF)·Wdot
    if (tid < 32) {
      float a = 0.f;
      #pragma unroll
      for (int f = 0; f < 32; f++) a += initd[f] * Wqd[f * 32 + tid];
      s_q[tid] = a * INV_SQRT_F;
    }
    __syncthreads();
    if (tid < 32) {
      float a = 0.f;
      #pragma unroll
      for (int f = 0; f < 32; f++) a += s_q[f] * Wdot[f * 32 + tid];
      s_c[tid] = a;
    }
    __syncthreads();
    {
      int f = tid >> 3, h = tid & 7;
      const float* w = &Wk2[h * 1024 + f * 32];
      float a = 0.f;
      #pragma unroll
      for (int g = 0; g < 32; g++) a += w[g] * s_c[g];
      ws_Mk[tid] = a * (1.0f / 1024.0f);   // tid == f*8+h
    }
  } else {  // blk == 255
    for (int idx = tid; idx < 1024; idx += 256) {
      int f = idx >> 5, g = idx & 31;
      float a = 0.f;
      #pragma unroll
      for (int k = 0; k < 32; k++) a += Wqg[f * 32 + k] * Wdot[k * 32 + g];
      ws_WQD[idx] = a;
    }
  }

  gbar(&ws_ctr[0], GRIDB);

  // ================= phase 1: stage-1 fused (scores, exp, T/den partials) =================
  {
    const int b = blk >> 3, jb = blk & 7;
    unsigned kmn = 0xFFFFFFFFu, kmx = 0u;
    if (tid < ZPB) { kmn = ws_zp[tid * 64 + b]; kmx = ws_zp[tid * 64 + 32 + b]; }
    s_ru[tid] = kmn; __syncthreads();
    for (int off = 128; off > 0; off >>= 1) { if (tid < off) s_ru[tid] = min(s_ru[tid], s_ru[tid + off]); __syncthreads(); }
    const unsigned rmn = s_ru[0]; __syncthreads();
    s_ru[tid] = kmx; __syncthreads();
    for (int off = 128; off > 0; off >>= 1) { if (tid < off) s_ru[tid] = max(s_ru[tid], s_ru[tid + off]); __syncthreads(); }
    const unsigned rmx = s_ru[0];
    const float zmin = key2f(rmn), zmax = key2f(rmx);

    if (tid < 64) { s_Wa[tid >> 3][tid & 7] = Wk1[tid]; s_Wb[tid >> 3][tid & 7] = Wv1[tid]; }
    s_Mk[tid >> 3][tid & 7] = ws_Mk[tid];
    const int ss0 = ws_seg[b], ss1 = ws_seg[b + 1];
    __syncthreads();

    const int cnt = ss1 - ss0;
    const int per = (cnt + 7) >> 3;
    const int lo = ss0 + jb * per;
    const int hi = min(lo + per, ss1);

    float Treg[8] = {0,0,0,0,0,0,0,0};
    float d0 = 0.f, d1 = 0.f;
    const int group = tid >> 6, gt = tid & 63, osh = gt >> 2, ofg = gt & 3;

    for (int base = lo; base < hi; base += 256) {
      int i = base + tid;
      if (i < hi) {
        float z = pos[3 * (size_t)i + 2];
        float len0 = z - zmin + DIST, len1 = zmax + DIST - z;
        float xv[32];
        const float4* xp = (const float4*)&xfeat[(size_t)i * 32];
        float4* xso = (float4*)s_xs[tid];
        #pragma unroll
        for (int q = 0; q < 8; q++) {
          float4 t = xp[q];
          xso[q] = t;
          xv[4*q] = t.x; xv[4*q+1] = t.y; xv[4*q+2] = t.z; xv[4*q+3] = t.w;
        }
        float u[8] = {0,0,0,0,0,0,0,0};
        #pragma unroll
        for (int f = 0; f < 32; f++) {
          float xf = xv[f];
          #pragma unroll
          for (int h = 0; h < 8; h++) u[h] += xf * s_Mk[f][h];
        }
        #pragma unroll
        for (int s = 0; s < 2; s++) {
          float L = s ? len1 : len0;
          float inv = 1.0f / (L + EPSV);
          float ee[8];
          #pragma unroll
          for (int j = 0; j < 8; j++) ee[j] = __sinf(s_bw[j] * L) * inv;
          float sc = 0.f;
          #pragma unroll
          for (int h = 0; h < 8; h++) {
            float a = 0.f;
            #pragma unroll
            for (int j = 0; j < 8; j++) a += ee[j] * s_Wa[j][h];
            sc += silu_f(a) * u[h];
          }
          // softmax without max-subtraction (exact ratio; clamp = overflow guard)
          float ex = __expf(fminf(fmaxf(sc, -60.f), 60.f));
          if (s) d1 += ex; else d0 += ex;
          #pragma unroll
          for (int h = 0; h < 8; h++) {
            float v = 0.f;
            #pragma unroll
            for (int j = 0; j < 8; j++) v += ee[j] * s_Wb[j][h];
            s_exh[tid][8*s + h] = ex * silu_f(v);
          }
        }
      } else {
        #pragma unroll
        for (int h = 0; h < 16; h++) s_exh[tid][h] = 0.f;
        float4* xso = (float4*)s_xs[tid];
        float4 z4 = make_float4(0.f, 0.f, 0.f, 0.f);
        #pragma unroll
        for (int q = 0; q < 8; q++) xso[q] = z4;
      }
      __syncthreads();
      const int cb = group * 64;
      for (int c = cb; c < cb + 64; c++) {
        float eh = s_exh[c][osh];
        const float* xr = &s_xs[c][ofg * 8];
        #pragma unroll
        for (int k = 0; k < 8; k++) Treg[k] += eh * xr[k];
      }
      __syncthreads();
    }
    #pragma unroll
    for (int k = 0; k < 8; k++) s_Tp[group][osh * 32 + ofg * 8 + k] = Treg[k];
    __syncthreads();
    const int slot = (b * 8 + jb);
    for (int idx = tid; idx < 512; idx += 256)
      ws_Tp[slot * 512 + idx] = s_Tp[0][idx] + s_Tp[1][idx] + s_Tp[2][idx] + s_Tp[3][idx];
    s_red[tid] = d0; __syncthreads();
    for (int off = 128; off > 0; off >>= 1) { if (tid < off) s_red[tid] += s_red[tid + off]; __syncthreads(); }
    if (tid == 0) ws_denp[slot * 2 + 0] = s_red[0];
    __syncthreads();
    s_red[tid] = d1; __syncthreads();
    for (int off = 128; off > 0; off >>= 1) { if (tid < off) s_red[tid] += s_red[tid + off]; __syncthreads(); }
    if (tid == 0) ws_denp[slot * 2 + 1] = s_red[0];
    if (jb == 0 && tid == 0) { ws_zf[2*b] = zmin; ws_zf[2*b+1] = zmax; }
  }

  gbar(&ws_ctr[1], GRIDB);

  // ================= phase 2+3: per-batch tables (redundant per block) + stage-2 =================
  {
    const int b = blk >> 3, jb = blk & 7;
    if (tid < 64) { s_Wa[tid >> 3][tid & 7] = Wkg1[tid]; s_Wb[tid >> 3][tid & 7] = Wvg1[tid]; }
    if (tid < 2) {
      float d = 0.f;
      #pragma unroll
      for (int j = 0; j < 8; j++) d += ws_denp[(b * 8 + j) * 2 + tid];
      s_den[tid] = d;
    }
    for (int idx = tid; idx < 512; idx += 256) {
      float a = 0.f;
      #pragma unroll
      for (int j = 0; j < 8; j++) a += ws_Tp[(b * 8 + j) * 512 + idx];
      s_T[idx] = a;
    }
    for (int idx = tid; idx < 1024; idx += 256) s_WQD[idx >> 5][idx & 31] = ws_WQD[idx];
    const float zmin = ws_zf[2*b], zmax = ws_zf[2*b+1];
    const int ss0 = ws_seg[b], ss1 = ws_seg[b + 1];
    __syncthreads();

    if (tid < 64) {
      int s = tid >> 5, g = tid & 31;
      float acc = 0.f;
      #pragma unroll
      for (int h = 0; h < 8; h++) {
        const float* wv = &Wv2[h * 1024 + g];
        const float* Ts = &s_T[(8 * s + h) * 32];
        #pragma unroll
        for (int f = 0; f < 32; f++) acc += Ts[f] * wv[f * 32];
      }
      float dn = s_den[s];
      float dv = initd[g] + (dn > 0.f ? acc * INV_SQRT_F / dn : 0.f);
      s_dm[s][g] = dv;
      if (jb == 0) out_dummy[b * 64 + tid] = dv;
    }
    __syncthreads();
    for (int idx = tid; idx < 512; idx += 256) {
      int sh = idx >> 5, g = idx & 31, s = sh >> 3, h = sh & 7;
      const float* wk = &Wkg2[h * 1024 + g];
      const float* wv = &Wvg2[h * 1024 + g];
      float a = 0.f, v = 0.f;
      #pragma unroll
      for (int f = 0; f < 32; f++) { float d = s_dm[s][f]; a += d * wk[f * 32]; v += d * wv[f * 32]; }
      s_Bkg[sh][g] = a;
      s_Bvg[sh][g] = v;
    }
    __syncthreads();
    for (int idx = tid; idx < 512; idx += 256) {
      int f = idx >> 4, sh = idx & 15;
      float a = 0.f;
      #pragma unroll
      for (int g = 0; g < 32; g++) a += s_WQD[f][g] * s_Bkg[sh][g];
      s_G[f][sh] = a * SC_STAGE2;
    }
    __syncthreads();

    const int cnt = ss1 - ss0;
    const int per = (cnt + 7) >> 3;
    const int lo = ss0 + jb * per;
    const int hi = min(lo + per, ss1);

    for (int i = lo + tid; i < hi; i += 256) {
      float z = pos[3 * (size_t)i + 2];
      float len0 = z - zmin + DIST, len1 = zmax + DIST - z;
      float ee[16];
      #pragma unroll
      for (int s = 0; s < 2; s++) {
        float L = s ? len1 : len0;
        float inv = 1.0f / (L + EPSV);
        #pragma unroll
        for (int j = 0; j < 8; j++) ee[8*s + j] = __sinf(s_bw[j] * L) * inv;
      }
      float hkg[16], hvg[16];
      #pragma unroll
      for (int s = 0; s < 2; s++) {
        #pragma unroll
        for (int h = 0; h < 8; h++) {
          float a = 0.f, v = 0.f;
          #pragma unroll
          for (int j = 0; j < 8; j++) { a += ee[8*s + j] * s_Wa[j][h]; v += ee[8*s + j] * s_Wb[j][h]; }
          hkg[8*s + h] = silu_f(a); hvg[8*s + h] = silu_f(v);
        }
      }
      float xv[32];
      const float4* xp = (const float4*)&xfeat[(size_t)i * 32];
      #pragma unroll
      for (int q = 0; q < 8; q++) { float4 t = xp[q]; xv[4*q] = t.x; xv[4*q+1] = t.y; xv[4*q+2] = t.z; xv[4*q+3] = t.w; }
      float ev[16] = {0,0,0,0,0,0,0,0,0,0,0,0,0,0,0,0};
      #pragma unroll
      for (int f = 0; f < 32; f++) {
        float xf = xv[f];
        #pragma unroll
        for (int sh = 0; sh < 16; sh++) ev[sh] += xf * s_G[f][sh];
      }
      float sc0 = 0.f, sc1 = 0.f;
      #pragma unroll
      for (int h = 0; h < 8; h++) { sc0 += hkg[h] * ev[h]; sc1 += hkg[8 + h] * ev[8 + h]; }
      float m = fmaxf(sc0, sc1);
      float a0 = __expf(sc0 - m), a1 = __expf(sc1 - m);
      float invd = 1.0f / (a0 + a1);
      float w0 = a0 * invd * INV_SQRT_F, w1 = a1 * invd * INV_SQRT_F;
      float ov[32];
      #pragma unroll
      for (int g = 0; g < 32; g++) ov[g] = xv[g];
      #pragma unroll
      for (int sh = 0; sh < 16; sh++) {
        float w = (sh < 8 ? w0 : w1) * hvg[sh];
        #pragma unroll
        for (int g = 0; g < 32; g++) ov[g] += w * s_Bvg[sh][g];
      }
      float4* op = (float4*)&out_node[(size_t)i * 32];
      #pragma unroll
      for (int q = 0; q < 8; q++) op[q] = make_float4(ov[4*q], ov[4*q+1], ov[4*q+2], ov[4*q+3]);
    }
  }
}

extern "C" void kernel_launch(void* const* d_in, const int* in_sizes, int n_in,
                              void* d_out, int out_size, void* d_ws, size_t ws_size,
                              hipStream_t stream)
{
  const float* pos   = (const float*)d_in[0];
  const int*   batch = (const int*)d_in[1];
  const float* xf    = (const float*)d_in[2];
  const float* bw    = (const float*)d_in[3];
  const float* Wqd   = (const float*)d_in[4];
  const float* Wk1   = (const float*)d_in[5];
  const float* Wk2   = (const float*)d_in[6];
  const float* Wv1   = (const float*)d_in[7];
  const float* Wv2   = (const float*)d_in[8];
  const float* Wqg   = (const float*)d_in[9];
  const float* Wkg1  = (const float*)d_in[10];
  const float* Wkg2  = (const float*)d_in[11];
  const float* Wvg1  = (const float*)d_in[12];
  const float* Wvg2  = (const float*)d_in[13];
  const float* Wdot  = (const float*)d_in[14];
  const float* initd = (const float*)d_in[15];
  int N = in_sizes[1];

  float* out_node  = (float*)d_out;
  float* out_dummy = out_node + (size_t)N * 32;
  float* ws        = (float*)d_ws;

  // zero the barrier counters (16 B) each launch — graph-capture-safe
  hipMemsetAsync(ws + 149232, 0, 16, stream);

  fused_all<<<GRIDB, 256, 0, stream>>>(pos, batch, xf, bw, Wqd, Wk1, Wk2, Wv1, Wv2,
                                       Wqg, Wkg1, Wkg2, Wvg1, Wvg2, Wdot, initd,
                                       out_node, out_dummy, ws, N);
}

// Round 6
// 64.329 us; speedup vs baseline: 1.9814x; 1.9814x over previous
//
#include <hip/hip_runtime.h>

#define NBATCH 32
#define DIST 5.0f
#define EPSV 1e-6f
#define INV_SQRT_F 0.17677669529663687f   // 1/sqrt(32)
#define SC_STAGE2 1.72633492e-4f          // 32^{-5/2}
#define KBS1 8    // stage-1 slices per batch -> 256 blocks
#define KBS2 16   // stage-2 slices per batch -> 512 blocks

__device__ __forceinline__ float silu_f(float v) { return v / (1.0f + __expf(-v)); }

// monotonic float <-> uint mapping for min/max via integer compares
__device__ __forceinline__ unsigned f2key(float f) {
  unsigned u = __float_as_uint(f);
  return (u & 0x80000000u) ? ~u : (u | 0x80000000u);
}
__device__ __forceinline__ float key2f(unsigned k) {
  return (k & 0x80000000u) ? __uint_as_float(k ^ 0x80000000u) : __uint_as_float(~k);
}

// ---------------- K1: z-key partials per tile + segoff + constants ----------------
extern "C" __global__ __launch_bounds__(256)
void prep_kernel(const float* __restrict__ pos, const int* __restrict__ batch,
                 const float* __restrict__ Wqd, const float* __restrict__ Wdot,
                 const float* __restrict__ Wqg, const float* __restrict__ Wk2,
                 const float* __restrict__ initd,
                 unsigned* __restrict__ ws_zp,   // [ZT][64]
                 int* __restrict__ ws_seg,       // [33]
                 float* __restrict__ ws_Mk,      // [256]
                 float* __restrict__ ws_WQD,     // [1024]
                 int N, int ZT)
{
  const int blk = blockIdx.x, tid = threadIdx.x;
  if (blk < ZT) {
    __shared__ unsigned s_pmin[NBATCH], s_pmax[NBATCH];
    if (tid < NBATCH) { s_pmin[tid] = 0xFFFFFFFFu; s_pmax[tid] = 0u; }
    __syncthreads();
    int i = (blk << 8) + tid;
    if (i < N) {
      int b = batch[i];
      unsigned k = f2key(pos[3 * (size_t)i + 2]);
      atomicMin(&s_pmin[b], k);
      atomicMax(&s_pmax[b], k);
      int bp = (i == 0) ? -1 : batch[i - 1];
      for (int bb = bp + 1; bb <= b; bb++) ws_seg[bb] = i;
      if (i == N - 1) for (int bb = b + 1; bb <= NBATCH; bb++) ws_seg[bb] = N;
    }
    __syncthreads();
    if (tid < NBATCH) {
      ws_zp[blk * 64 + tid]      = s_pmin[tid];
      ws_zp[blk * 64 + 32 + tid] = s_pmax[tid];
    }
  } else if (blk == ZT) {
    // Mk[f][h] = (1/1024) * sum_g Wk2[h,f*32+g] * c[g],  c = (initd·Wqd·invsF)·Wdot
    __shared__ float s_q[32], s_c[32];
    if (tid < 32) {
      float a = 0.f;
      #pragma unroll
      for (int f = 0; f < 32; f++) a += initd[f] * Wqd[f * 32 + tid];
      s_q[tid] = a * INV_SQRT_F;
    }
    __syncthreads();
    if (tid < 32) {
      float a = 0.f;
      #pragma unroll
      for (int f = 0; f < 32; f++) a += s_q[f] * Wdot[f * 32 + tid];
      s_c[tid] = a;
    }
    __syncthreads();
    {
      int f = tid >> 3, h = tid & 7;
      const float* w = &Wk2[h * 1024 + f * 32];
      float a = 0.f;
      #pragma unroll
      for (int g = 0; g < 32; g++) a += w[g] * s_c[g];
      ws_Mk[tid] = a * (1.0f / 1024.0f);   // tid == f*8+h
    }
  } else {
    for (int idx = tid; idx < 1024; idx += 256) {
      int f = idx >> 5, g = idx & 31;
      float a = 0.f;
      #pragma unroll
      for (int k = 0; k < 32; k++) a += Wqg[f * 32 + k] * Wdot[k * 32 + g];
      ws_WQD[idx] = a;
    }
  }
}

// ---------------- K2: stage-1 fused (z-reduce, scores, exp, T/den partial slots) ----------------
extern "C" __global__ __launch_bounds__(256)
void stage1_kernel(const float* __restrict__ pos,
                   const float* __restrict__ xfeat,
                   const float* __restrict__ bw,
                   const float* __restrict__ Wk1,
                   const float* __restrict__ Wv1,
                   const int*   __restrict__ ws_seg,
                   const unsigned* __restrict__ ws_zp,
                   const float* __restrict__ ws_Mk,
                   float* __restrict__ ws_Tp,    // [NB*KBS1][512]
                   float* __restrict__ ws_denp,  // [NB*KBS1][2]
                   float* __restrict__ ws_zf,    // [NB][2]
                   int N, int ZT)
{
  const int b = blockIdx.x >> 3, jb = blockIdx.x & 7;
  const int tid = threadIdx.x;

  __shared__ unsigned s_ru[256];
  __shared__ float s_red[256];
  __shared__ float s_bw[8];
  __shared__ float s_Wa[8][8], s_Wb[8][8];
  __shared__ float s_Mk[32][8];
  __shared__ float s_exh[256][16];
  __shared__ float s_xs[256][32];
  __shared__ float s_Tp[4][512];

  // inline z reduction over ZT partial tiles
  unsigned kmn = 0xFFFFFFFFu, kmx = 0u;
  for (int t = tid; t < ZT; t += 256) {
    kmn = min(kmn, ws_zp[t * 64 + b]);
    kmx = max(kmx, ws_zp[t * 64 + 32 + b]);
  }
  s_ru[tid] = kmn; __syncthreads();
  for (int off = 128; off > 0; off >>= 1) { if (tid < off) s_ru[tid] = min(s_ru[tid], s_ru[tid + off]); __syncthreads(); }
  const unsigned rmn = s_ru[0]; __syncthreads();
  s_ru[tid] = kmx; __syncthreads();
  for (int off = 128; off > 0; off >>= 1) { if (tid < off) s_ru[tid] = max(s_ru[tid], s_ru[tid + off]); __syncthreads(); }
  const unsigned rmx = s_ru[0];
  const float zmin = key2f(rmn), zmax = key2f(rmx);

  if (tid < 8) s_bw[tid] = bw[tid];
  if (tid < 64) { s_Wa[tid >> 3][tid & 7] = Wk1[tid]; s_Wb[tid >> 3][tid & 7] = Wv1[tid]; }
  s_Mk[tid >> 3][tid & 7] = ws_Mk[tid];
  const int ss0 = ws_seg[b], ss1 = ws_seg[b + 1];
  __syncthreads();

  const int cnt = ss1 - ss0;
  const int per = (cnt + KBS1 - 1) / KBS1;
  const int lo = ss0 + jb * per;
  const int hi = min(lo + per, ss1);

  float Treg[8] = {0,0,0,0,0,0,0,0};
  float d0 = 0.f, d1 = 0.f;
  const int group = tid >> 6, gt = tid & 63, osh = gt >> 2, ofg = gt & 3;

  for (int base = lo; base < hi; base += 256) {
    int i = base + tid;
    if (i < hi) {
      float z = pos[3 * (size_t)i + 2];
      float len0 = z - zmin + DIST, len1 = zmax + DIST - z;
      float xv[32];
      const float4* xp = (const float4*)&xfeat[(size_t)i * 32];
      float4* xso = (float4*)s_xs[tid];
      #pragma unroll
      for (int q = 0; q < 8; q++) {
        float4 t = xp[q];
        xso[q] = t;
        xv[4*q] = t.x; xv[4*q+1] = t.y; xv[4*q+2] = t.z; xv[4*q+3] = t.w;
      }
      float u[8] = {0,0,0,0,0,0,0,0};
      #pragma unroll
      for (int f = 0; f < 32; f++) {
        float xf = xv[f];
        #pragma unroll
        for (int h = 0; h < 8; h++) u[h] += xf * s_Mk[f][h];
      }
      #pragma unroll
      for (int s = 0; s < 2; s++) {
        float L = s ? len1 : len0;
        float inv = 1.0f / (L + EPSV);
        float ee[8];
        #pragma unroll
        for (int j = 0; j < 8; j++) ee[j] = __sinf(s_bw[j] * L) * inv;
        float sc = 0.f;
        #pragma unroll
        for (int h = 0; h < 8; h++) {
          float a = 0.f;
          #pragma unroll
          for (int j = 0; j < 8; j++) a += ee[j] * s_Wa[j][h];
          sc += silu_f(a) * u[h];
        }
        // softmax without max-subtraction (exact ratio; clamp = overflow guard)
        float ex = __expf(fminf(fmaxf(sc, -60.f), 60.f));
        if (s) d1 += ex; else d0 += ex;
        #pragma unroll
        for (int h = 0; h < 8; h++) {
          float v = 0.f;
          #pragma unroll
          for (int j = 0; j < 8; j++) v += ee[j] * s_Wb[j][h];
          s_exh[tid][8*s + h] = ex * silu_f(v);
        }
      }
    } else {
      #pragma unroll
      for (int h = 0; h < 16; h++) s_exh[tid][h] = 0.f;
      float4* xso = (float4*)s_xs[tid];
      float4 z4 = make_float4(0.f, 0.f, 0.f, 0.f);
      #pragma unroll
      for (int q = 0; q < 8; q++) xso[q] = z4;
    }
    __syncthreads();
    const int cb = group * 64;
    for (int c = cb; c < cb + 64; c++) {
      float eh = s_exh[c][osh];
      const float* xr = &s_xs[c][ofg * 8];
      #pragma unroll
      for (int k = 0; k < 8; k++) Treg[k] += eh * xr[k];
    }
    __syncthreads();
  }
  #pragma unroll
  for (int k = 0; k < 8; k++) s_Tp[group][osh * 32 + ofg * 8 + k] = Treg[k];
  __syncthreads();
  const int slot = b * KBS1 + jb;
  for (int idx = tid; idx < 512; idx += 256)
    ws_Tp[slot * 512 + idx] = s_Tp[0][idx] + s_Tp[1][idx] + s_Tp[2][idx] + s_Tp[3][idx];
  s_red[tid] = d0; __syncthreads();
  for (int off = 128; off > 0; off >>= 1) { if (tid < off) s_red[tid] += s_red[tid + off]; __syncthreads(); }
  if (tid == 0) ws_denp[slot * 2 + 0] = s_red[0];
  __syncthreads();
  s_red[tid] = d1; __syncthreads();
  for (int off = 128; off > 0; off >>= 1) { if (tid < off) s_red[tid] += s_red[tid + off]; __syncthreads(); }
  if (tid == 0) ws_denp[slot * 2 + 1] = s_red[0];
  if (jb == 0 && tid == 0) { ws_zf[2*b] = zmin; ws_zf[2*b+1] = zmax; }
}

// ---------------- K3: per-batch tables (redundant per block) + stage-2 output ----------------
extern "C" __global__ __launch_bounds__(256)
void stage2_kernel(const float* __restrict__ pos,
                   const float* __restrict__ xfeat,
                   const float* __restrict__ bw,
                   const float* __restrict__ Wkg1, const float* __restrict__ Wkg2,
                   const float* __restrict__ Wvg1, const float* __restrict__ Wvg2,
                   const float* __restrict__ Wv2,  const float* __restrict__ initd,
                   const int*   __restrict__ ws_seg,
                   const float* __restrict__ ws_Tp,
                   const float* __restrict__ ws_denp,
                   const float* __restrict__ ws_zf,
                   const float* __restrict__ ws_WQD,
                   float* __restrict__ out_node, float* __restrict__ out_dummy,
                   int N)
{
  const int b = blockIdx.x >> 4, jb = blockIdx.x & 15;
  const int tid = threadIdx.x;

  __shared__ float s_bw[8];
  __shared__ float s_Wa[8][8], s_Wb[8][8];
  __shared__ float s_T[512];
  __shared__ float s_den[2];
  __shared__ float s_dm[2][32];
  __shared__ float s_WQD[32][32];
  __shared__ float s_Bkg[16][32];
  __shared__ float s_Bvg[16][32];
  __shared__ float s_G[32][16];

  if (tid < 8) s_bw[tid] = bw[tid];
  if (tid < 64) { s_Wa[tid >> 3][tid & 7] = Wkg1[tid]; s_Wb[tid >> 3][tid & 7] = Wvg1[tid]; }
  if (tid < 2) {
    float d = 0.f;
    #pragma unroll
    for (int j = 0; j < KBS1; j++) d += ws_denp[(b * KBS1 + j) * 2 + tid];
    s_den[tid] = d;
  }
  for (int idx = tid; idx < 512; idx += 256) {
    float a = 0.f;
    #pragma unroll
    for (int j = 0; j < KBS1; j++) a += ws_Tp[(b * KBS1 + j) * 512 + idx];
    s_T[idx] = a;
  }
  for (int idx = tid; idx < 1024; idx += 256) s_WQD[idx >> 5][idx & 31] = ws_WQD[idx];
  const float zmin = ws_zf[2*b], zmax = ws_zf[2*b+1];
  const int ss0 = ws_seg[b], ss1 = ws_seg[b + 1];
  __syncthreads();

  if (tid < 64) {
    int s = tid >> 5, g = tid & 31;
    float acc = 0.f;
    #pragma unroll
    for (int h = 0; h < 8; h++) {
      const float* wv = &Wv2[h * 1024 + g];
      const float* Ts = &s_T[(8 * s + h) * 32];
      #pragma unroll
      for (int f = 0; f < 32; f++) acc += Ts[f] * wv[f * 32];
    }
    float dn = s_den[s];
    float dv = initd[g] + (dn > 0.f ? acc * INV_SQRT_F / dn : 0.f);
    s_dm[s][g] = dv;
    if (jb == 0) out_dummy[b * 64 + tid] = dv;
  }
  __syncthreads();
  for (int idx = tid; idx < 512; idx += 256) {
    int sh = idx >> 5, g = idx & 31, s = sh >> 3, h = sh & 7;
    const float* wk = &Wkg2[h * 1024 + g];
    const float* wv = &Wvg2[h * 1024 + g];
    float a = 0.f, v = 0.f;
    #pragma unroll
    for (int f = 0; f < 32; f++) { float d = s_dm[s][f]; a += d * wk[f * 32]; v += d * wv[f * 32]; }
    s_Bkg[sh][g] = a;
    s_Bvg[sh][g] = v;
  }
  __syncthreads();
  for (int idx = tid; idx < 512; idx += 256) {
    int f = idx >> 4, sh = idx & 15;
    float a = 0.f;
    #pragma unroll
    for (int g = 0; g < 32; g++) a += s_WQD[f][g] * s_Bkg[sh][g];
    s_G[f][sh] = a * SC_STAGE2;
  }
  __syncthreads();

  const int cnt = ss1 - ss0;
  const int per = (cnt + KBS2 - 1) / KBS2;
  const int lo = ss0 + jb * per;
  const int hi = min(lo + per, ss1);

  for (int i = lo + tid; i < hi; i += 256) {
    float z = pos[3 * (size_t)i + 2];
    float len0 = z - zmin + DIST, len1 = zmax + DIST - z;
    float ee[16];
    #pragma unroll
    for (int s = 0; s < 2; s++) {
      float L = s ? len1 : len0;
      float inv = 1.0f / (L + EPSV);
      #pragma unroll
      for (int j = 0; j < 8; j++) ee[8*s + j] = __sinf(s_bw[j] * L) * inv;
    }
    float hkg[16], hvg[16];
    #pragma unroll
    for (int s = 0; s < 2; s++) {
      #pragma unroll
      for (int h = 0; h < 8; h++) {
        float a = 0.f, v = 0.f;
        #pragma unroll
        for (int j = 0; j < 8; j++) { a += ee[8*s + j] * s_Wa[j][h]; v += ee[8*s + j] * s_Wb[j][h]; }
        hkg[8*s + h] = silu_f(a); hvg[8*s + h] = silu_f(v);
      }
    }
    float xv[32];
    const float4* xp = (const float4*)&xfeat[(size_t)i * 32];
    #pragma unroll
    for (int q = 0; q < 8; q++) { float4 t = xp[q]; xv[4*q] = t.x; xv[4*q+1] = t.y; xv[4*q+2] = t.z; xv[4*q+3] = t.w; }
    float ev[16] = {0,0,0,0,0,0,0,0,0,0,0,0,0,0,0,0};
    #pragma unroll
    for (int f = 0; f < 32; f++) {
      float xf = xv[f];
      #pragma unroll
      for (int sh = 0; sh < 16; sh++) ev[sh] += xf * s_G[f][sh];
    }
    float sc0 = 0.f, sc1 = 0.f;
    #pragma unroll
    for (int h = 0; h < 8; h++) { sc0 += hkg[h] * ev[h]; sc1 += hkg[8 + h] * ev[8 + h]; }
    float m = fmaxf(sc0, sc1);
    float a0 = __expf(sc0 - m), a1 = __expf(sc1 - m);
    float invd = 1.0f / (a0 + a1);
    float w0 = a0 * invd * INV_SQRT_F, w1 = a1 * invd * INV_SQRT_F;
    float ov[32];
    #pragma unroll
    for (int g = 0; g < 32; g++) ov[g] = xv[g];
    #pragma unroll
    for (int sh = 0; sh < 16; sh++) {
      float w = (sh < 8 ? w0 : w1) * hvg[sh];
      #pragma unroll
      for (int g = 0; g < 32; g++) ov[g] += w * s_Bvg[sh][g];
    }
    float4* op = (float4*)&out_node[(size_t)i * 32];
    #pragma unroll
    for (int q = 0; q < 8; q++) op[q] = make_float4(ov[4*q], ov[4*q+1], ov[4*q+2], ov[4*q+3]);
  }
}

extern "C" void kernel_launch(void* const* d_in, const int* in_sizes, int n_in,
                              void* d_out, int out_size, void* d_ws, size_t ws_size,
                              hipStream_t stream)
{
  const float* pos   = (const float*)d_in[0];
  const int*   batch = (const int*)d_in[1];
  const float* xf    = (const float*)d_in[2];
  const float* bw    = (const float*)d_in[3];
  const float* Wqd   = (const float*)d_in[4];
  const float* Wk1   = (const float*)d_in[5];
  const float* Wk2   = (const float*)d_in[6];
  const float* Wv1   = (const float*)d_in[7];
  const float* Wv2   = (const float*)d_in[8];
  const float* Wqg   = (const float*)d_in[9];
  const float* Wkg1  = (const float*)d_in[10];
  const float* Wkg2  = (const float*)d_in[11];
  const float* Wvg1  = (const float*)d_in[12];
  const float* Wvg2  = (const float*)d_in[13];
  const float* Wdot  = (const float*)d_in[14];
  const float* initd = (const float*)d_in[15];
  int N = in_sizes[1];

  float* out_node  = (float*)d_out;
  float* out_dummy = out_node + (size_t)N * 32;

  // workspace layout (float offsets) — every word written before read, each call
  float*    ws      = (float*)d_ws;
  float*    ws_Tp   = ws;                        // 32*8*512 = 131072
  float*    ws_denp = ws + 131072;               // 512
  float*    ws_zf   = ws + 131584;               // 64
  int*      ws_seg  = (int*)(ws + 131648);       // 33 (+pad)
  float*    ws_Mk   = ws + 131696;               // 256
  float*    ws_WQD  = ws + 131952;               // 1024
  unsigned* ws_zp   = (unsigned*)(ws + 132976);  // ZT*64

  const int ZT = (N + 255) >> 8;

  prep_kernel<<<ZT + 2, 256, 0, stream>>>(pos, batch, Wqd, Wdot, Wqg, Wk2, initd,
                                          ws_zp, ws_seg, ws_Mk, ws_WQD, N, ZT);

  stage1_kernel<<<NBATCH * KBS1, 256, 0, stream>>>(pos, xf, bw, Wk1, Wv1, ws_seg, ws_zp,
                                                   ws_Mk, ws_Tp, ws_denp, ws_zf, N, ZT);

  stage2_kernel<<<NBATCH * KBS2, 256, 0, stream>>>(pos, xf, bw, Wkg1, Wkg2, Wvg1, Wvg2,
                                                   Wv2, initd, ws_seg, ws_Tp, ws_denp,
                                                   ws_zf, ws_WQD, out_node, out_dummy, N);
}

// Round 7
// 61.488 us; speedup vs baseline: 2.0729x; 1.0462x over previous
//
#include <hip/hip_runtime.h>

#define NBATCH 32
#define DIST 5.0f
#define EPSV 1e-6f
#define INV_SQRT_F 0.17677669529663687f   // 1/sqrt(32)
#define SC_STAGE2 1.72633492e-4f          // 32^{-5/2}
#define KBS1 8    // stage-1 slices per batch -> 256 blocks
#define KBS2 16   // stage-2 slices per batch -> 512 blocks

__device__ __forceinline__ float silu_f(float v) { return __fdividef(v, 1.0f + __expf(-v)); }

// monotonic float <-> uint mapping for min/max via integer compares
__device__ __forceinline__ unsigned f2key(float f) {
  unsigned u = __float_as_uint(f);
  return (u & 0x80000000u) ? ~u : (u | 0x80000000u);
}
__device__ __forceinline__ float key2f(unsigned k) {
  return (k & 0x80000000u) ? __uint_as_float(k ^ 0x80000000u) : __uint_as_float(~k);
}

// ---------------- K1: z-key partials per tile + segoff + constants ----------------
extern "C" __global__ __launch_bounds__(256)
void prep_kernel(const float* __restrict__ pos, const int* __restrict__ batch,
                 const float* __restrict__ Wqd, const float* __restrict__ Wdot,
                 const float* __restrict__ Wqg, const float* __restrict__ Wk2,
                 const float* __restrict__ initd,
                 unsigned* __restrict__ ws_zp,   // [ZT][64]
                 int* __restrict__ ws_seg,       // [33]
                 float* __restrict__ ws_Mk,      // [256]
                 float* __restrict__ ws_WQD,     // [1024]
                 int N, int ZT)
{
  const int blk = blockIdx.x, tid = threadIdx.x;
  if (blk < ZT) {
    __shared__ unsigned s_pmin[NBATCH], s_pmax[NBATCH];
    if (tid < NBATCH) { s_pmin[tid] = 0xFFFFFFFFu; s_pmax[tid] = 0u; }
    __syncthreads();
    int i = (blk << 8) + tid;
    if (i < N) {
      int b = batch[i];
      unsigned k = f2key(pos[3 * (size_t)i + 2]);
      atomicMin(&s_pmin[b], k);
      atomicMax(&s_pmax[b], k);
      int bp = (i == 0) ? -1 : batch[i - 1];
      for (int bb = bp + 1; bb <= b; bb++) ws_seg[bb] = i;
      if (i == N - 1) for (int bb = b + 1; bb <= NBATCH; bb++) ws_seg[bb] = N;
    }
    __syncthreads();
    if (tid < NBATCH) {
      ws_zp[blk * 64 + tid]      = s_pmin[tid];
      ws_zp[blk * 64 + 32 + tid] = s_pmax[tid];
    }
  } else if (blk == ZT) {
    // Mk[f][h] = (1/1024) * sum_g Wk2[h,f*32+g] * c[g],  c = (initd·Wqd·invsF)·Wdot
    __shared__ float s_q[32], s_c[32];
    if (tid < 32) {
      float a = 0.f;
      #pragma unroll
      for (int f = 0; f < 32; f++) a += initd[f] * Wqd[f * 32 + tid];
      s_q[tid] = a * INV_SQRT_F;
    }
    __syncthreads();
    if (tid < 32) {
      float a = 0.f;
      #pragma unroll
      for (int f = 0; f < 32; f++) a += s_q[f] * Wdot[f * 32 + tid];
      s_c[tid] = a;
    }
    __syncthreads();
    {
      int f = tid >> 3, h = tid & 7;
      const float* w = &Wk2[h * 1024 + f * 32];
      float a = 0.f;
      #pragma unroll
      for (int g = 0; g < 32; g++) a += w[g] * s_c[g];
      ws_Mk[tid] = a * (1.0f / 1024.0f);   // tid == f*8+h
    }
  } else {
    for (int idx = tid; idx < 1024; idx += 256) {
      int f = idx >> 5, g = idx & 31;
      float a = 0.f;
      #pragma unroll
      for (int k = 0; k < 32; k++) a += Wqg[f * 32 + k] * Wdot[k * 32 + g];
      ws_WQD[idx] = a;
    }
  }
}

// ---------------- K2: stage-1 fused (z-reduce, scores, exp, T/den partial slots) ----------------
extern "C" __global__ __launch_bounds__(256)
void stage1_kernel(const float* __restrict__ pos,
                   const float* __restrict__ xfeat,
                   const float* __restrict__ bw,
                   const float* __restrict__ Wk1,
                   const float* __restrict__ Wv1,
                   const int*   __restrict__ ws_seg,
                   const unsigned* __restrict__ ws_zp,
                   const float* __restrict__ ws_Mk,
                   float* __restrict__ ws_Tp,    // [NB*KBS1][512]
                   float* __restrict__ ws_denp,  // [NB*KBS1][2]
                   float* __restrict__ ws_zf,    // [NB][2]
                   int N, int ZT)
{
  const int b = blockIdx.x >> 3, jb = blockIdx.x & 7;
  const int tid = threadIdx.x;

  __shared__ unsigned s_ru[256];
  __shared__ float s_red[256];
  __shared__ float s_bw[8];
  __shared__ float s_Wa[8][8], s_Wb[8][8];
  __shared__ float s_Mk[32][8];
  __shared__ float s_exh[256][17];   // pad 17: writes 2-way (free), reads conflict-free
  __shared__ float s_xs[256][36];    // pad 36: float4-aligned rows, reads conflict-free
  __shared__ float s_Tp[4][512];

  // inline z reduction over ZT partial tiles
  unsigned kmn = 0xFFFFFFFFu, kmx = 0u;
  for (int t = tid; t < ZT; t += 256) {
    kmn = min(kmn, ws_zp[t * 64 + b]);
    kmx = max(kmx, ws_zp[t * 64 + 32 + b]);
  }
  s_ru[tid] = kmn; __syncthreads();
  for (int off = 128; off > 0; off >>= 1) { if (tid < off) s_ru[tid] = min(s_ru[tid], s_ru[tid + off]); __syncthreads(); }
  const unsigned rmn = s_ru[0]; __syncthreads();
  s_ru[tid] = kmx; __syncthreads();
  for (int off = 128; off > 0; off >>= 1) { if (tid < off) s_ru[tid] = max(s_ru[tid], s_ru[tid + off]); __syncthreads(); }
  const unsigned rmx = s_ru[0];
  const float zmin = key2f(rmn), zmax = key2f(rmx);

  if (tid < 8) s_bw[tid] = bw[tid];
  if (tid < 64) { s_Wa[tid >> 3][tid & 7] = Wk1[tid]; s_Wb[tid >> 3][tid & 7] = Wv1[tid]; }
  s_Mk[tid >> 3][tid & 7] = ws_Mk[tid];
  const int ss0 = ws_seg[b], ss1 = ws_seg[b + 1];
  __syncthreads();

  const int cnt = ss1 - ss0;
  const int per = (cnt + KBS1 - 1) / KBS1;
  const int lo = ss0 + jb * per;
  const int hi = min(lo + per, ss1);

  float Treg[8] = {0,0,0,0,0,0,0,0};
  float d0 = 0.f, d1 = 0.f;
  const int group = tid >> 6, gt = tid & 63, osh = gt >> 2, ofg = gt & 3;

  for (int base = lo; base < hi; base += 256) {
    int i = base + tid;
    if (i < hi) {
      float z = pos[3 * (size_t)i + 2];
      float len0 = z - zmin + DIST, len1 = zmax + DIST - z;
      float xv[32];
      const float4* xp = (const float4*)&xfeat[(size_t)i * 32];
      float4* xso = (float4*)s_xs[tid];
      #pragma unroll
      for (int q = 0; q < 8; q++) {
        float4 t = xp[q];
        xso[q] = t;
        xv[4*q] = t.x; xv[4*q+1] = t.y; xv[4*q+2] = t.z; xv[4*q+3] = t.w;
      }
      float u[8] = {0,0,0,0,0,0,0,0};
      #pragma unroll
      for (int f = 0; f < 32; f++) {
        float xf = xv[f];
        #pragma unroll
        for (int h = 0; h < 8; h++) u[h] += xf * s_Mk[f][h];
      }
      #pragma unroll
      for (int s = 0; s < 2; s++) {
        float L = s ? len1 : len0;
        float inv = __fdividef(1.0f, L + EPSV);
        float ee[8];
        #pragma unroll
        for (int j = 0; j < 8; j++) ee[j] = __sinf(s_bw[j] * L) * inv;
        float sc = 0.f;
        #pragma unroll
        for (int h = 0; h < 8; h++) {
          float a = 0.f;
          #pragma unroll
          for (int j = 0; j < 8; j++) a += ee[j] * s_Wa[j][h];
          sc += silu_f(a) * u[h];
        }
        // softmax without max-subtraction (exact ratio; clamp = overflow guard)
        float ex = __expf(fminf(fmaxf(sc, -60.f), 60.f));
        if (s) d1 += ex; else d0 += ex;
        #pragma unroll
        for (int h = 0; h < 8; h++) {
          float v = 0.f;
          #pragma unroll
          for (int j = 0; j < 8; j++) v += ee[j] * s_Wb[j][h];
          s_exh[tid][8*s + h] = ex * silu_f(v);
        }
      }
    } else {
      #pragma unroll
      for (int h = 0; h < 16; h++) s_exh[tid][h] = 0.f;
      float4* xso = (float4*)s_xs[tid];
      float4 z4 = make_float4(0.f, 0.f, 0.f, 0.f);
      #pragma unroll
      for (int q = 0; q < 8; q++) xso[q] = z4;
    }
    __syncthreads();
    const int cb = group * 64;
    for (int c = cb; c < cb + 64; c++) {
      float eh = s_exh[c][osh];
      const float4* xr4 = (const float4*)&s_xs[c][ofg * 8];
      float4 xa = xr4[0], xb = xr4[1];
      Treg[0] += eh * xa.x; Treg[1] += eh * xa.y; Treg[2] += eh * xa.z; Treg[3] += eh * xa.w;
      Treg[4] += eh * xb.x; Treg[5] += eh * xb.y; Treg[6] += eh * xb.z; Treg[7] += eh * xb.w;
    }
    __syncthreads();
  }
  #pragma unroll
  for (int k = 0; k < 8; k++) s_Tp[group][osh * 32 + ofg * 8 + k] = Treg[k];
  __syncthreads();
  const int slot = b * KBS1 + jb;
  for (int idx = tid; idx < 512; idx += 256)
    ws_Tp[slot * 512 + idx] = s_Tp[0][idx] + s_Tp[1][idx] + s_Tp[2][idx] + s_Tp[3][idx];
  s_red[tid] = d0; __syncthreads();
  for (int off = 128; off > 0; off >>= 1) { if (tid < off) s_red[tid] += s_red[tid + off]; __syncthreads(); }
  if (tid == 0) ws_denp[slot * 2 + 0] = s_red[0];
  __syncthreads();
  s_red[tid] = d1; __syncthreads();
  for (int off = 128; off > 0; off >>= 1) { if (tid < off) s_red[tid] += s_red[tid + off]; __syncthreads(); }
  if (tid == 0) ws_denp[slot * 2 + 1] = s_red[0];
  if (jb == 0 && tid == 0) { ws_zf[2*b] = zmin; ws_zf[2*b+1] = zmax; }
}

// ---------------- K3: per-batch tables (redundant per block) + stage-2 output ----------------
extern "C" __global__ __launch_bounds__(256)
void stage2_kernel(const float* __restrict__ pos,
                   const float* __restrict__ xfeat,
                   const float* __restrict__ bw,
                   const float* __restrict__ Wkg1, const float* __restrict__ Wkg2,
                   const float* __restrict__ Wvg1, const float* __restrict__ Wvg2,
                   const float* __restrict__ Wv2,  const float* __restrict__ initd,
                   const int*   __restrict__ ws_seg,
                   const float* __restrict__ ws_Tp,
                   const float* __restrict__ ws_denp,
                   const float* __restrict__ ws_zf,
                   const float* __restrict__ ws_WQD,
                   float* __restrict__ out_node, float* __restrict__ out_dummy,
                   int N)
{
  const int b = blockIdx.x >> 4, jb = blockIdx.x & 15;
  const int tid = threadIdx.x;

  __shared__ float s_bw[8];
  __shared__ float s_Wa[8][8], s_Wb[8][8];
  __shared__ float s_T[512];
  __shared__ float s_den[2];
  __shared__ float s_dp[4][2][32];
  __shared__ float s_dm[2][32];
  __shared__ float s_WQD[32][32];
  __shared__ float s_Bkg[16][32];
  __shared__ float s_Bvg[16][32];
  __shared__ float s_G[32][16];

  if (tid < 8) s_bw[tid] = bw[tid];
  if (tid < 64) { s_Wa[tid >> 3][tid & 7] = Wkg1[tid]; s_Wb[tid >> 3][tid & 7] = Wvg1[tid]; }
  if (tid < 2) {
    float d = 0.f;
    #pragma unroll
    for (int j = 0; j < KBS1; j++) d += ws_denp[(b * KBS1 + j) * 2 + tid];
    s_den[tid] = d;
  }
  for (int idx = tid; idx < 512; idx += 256) {
    float a = 0.f;
    #pragma unroll
    for (int j = 0; j < KBS1; j++) a += ws_Tp[(b * KBS1 + j) * 512 + idx];
    s_T[idx] = a;
  }
  for (int idx = tid; idx < 1024; idx += 256) s_WQD[idx >> 5][idx & 31] = ws_WQD[idx];
  const float zmin = ws_zf[2*b], zmax = ws_zf[2*b+1];
  const int ss0 = ws_seg[b], ss1 = ws_seg[b + 1];
  __syncthreads();

  // parallel dummy: thread (fq, s, g) accumulates f in [fq*8, fq*8+8)
  {
    int g = tid & 31, s = (tid >> 5) & 1, fq = tid >> 6;
    float acc = 0.f;
    #pragma unroll
    for (int h = 0; h < 8; h++) {
      #pragma unroll
      for (int f8 = 0; f8 < 8; f8++) {
        int f = fq * 8 + f8;
        acc += s_T[(8 * s + h) * 32 + f] * Wv2[h * 1024 + f * 32 + g];
      }
    }
    s_dp[fq][s][g] = acc;
  }
  __syncthreads();
  if (tid < 64) {
    int s = tid >> 5, g = tid & 31;
    float acc = s_dp[0][s][g] + s_dp[1][s][g] + s_dp[2][s][g] + s_dp[3][s][g];
    float dn = s_den[s];
    float dv = initd[g] + (dn > 0.f ? acc * INV_SQRT_F * __fdividef(1.0f, dn) : 0.f);
    s_dm[s][g] = dv;
    if (jb == 0) out_dummy[b * 64 + tid] = dv;
  }
  __syncthreads();
  for (int idx = tid; idx < 512; idx += 256) {
    int sh = idx >> 5, g = idx & 31, s = sh >> 3, h = sh & 7;
    const float* wk = &Wkg2[h * 1024 + g];
    const float* wv = &Wvg2[h * 1024 + g];
    float a = 0.f, v = 0.f;
    #pragma unroll
    for (int f = 0; f < 32; f++) { float d = s_dm[s][f]; a += d * wk[f * 32]; v += d * wv[f * 32]; }
    s_Bkg[sh][g] = a;
    s_Bvg[sh][g] = v;
  }
  __syncthreads();
  for (int idx = tid; idx < 512; idx += 256) {
    int f = idx >> 4, sh = idx & 15;
    float a = 0.f;
    #pragma unroll
    for (int g = 0; g < 32; g++) a += s_WQD[f][g] * s_Bkg[sh][g];
    s_G[f][sh] = a * SC_STAGE2;
  }
  __syncthreads();

  const int cnt = ss1 - ss0;
  const int per = (cnt + KBS2 - 1) / KBS2;
  const int lo = ss0 + tid + jb * per;
  const int hi = min(ss0 + (jb + 1) * per, ss1);

  for (int i = lo; i < hi; i += 256) {
    float z = pos[3 * (size_t)i + 2];
    float len0 = z - zmin + DIST, len1 = zmax + DIST - z;
    float ee[16];
    #pragma unroll
    for (int s = 0; s < 2; s++) {
      float L = s ? len1 : len0;
      float inv = __fdividef(1.0f, L + EPSV);
      #pragma unroll
      for (int j = 0; j < 8; j++) ee[8*s + j] = __sinf(s_bw[j] * L) * inv;
    }
    float hkg[16], hvg[16];
    #pragma unroll
    for (int s = 0; s < 2; s++) {
      #pragma unroll
      for (int h = 0; h < 8; h++) {
        float a = 0.f, v = 0.f;
        #pragma unroll
        for (int j = 0; j < 8; j++) { a += ee[8*s + j] * s_Wa[j][h]; v += ee[8*s + j] * s_Wb[j][h]; }
        hkg[8*s + h] = silu_f(a); hvg[8*s + h] = silu_f(v);
      }
    }
    float xv[32];
    const float4* xp = (const float4*)&xfeat[(size_t)i * 32];
    #pragma unroll
    for (int q = 0; q < 8; q++) { float4 t = xp[q]; xv[4*q] = t.x; xv[4*q+1] = t.y; xv[4*q+2] = t.z; xv[4*q+3] = t.w; }
    float ev[16] = {0,0,0,0,0,0,0,0,0,0,0,0,0,0,0,0};
    #pragma unroll
    for (int f = 0; f < 32; f++) {
      float xf = xv[f];
      #pragma unroll
      for (int sh = 0; sh < 16; sh++) ev[sh] += xf * s_G[f][sh];
    }
    float sc0 = 0.f, sc1 = 0.f;
    #pragma unroll
    for (int h = 0; h < 8; h++) { sc0 += hkg[h] * ev[h]; sc1 += hkg[8 + h] * ev[8 + h]; }
    float m = fmaxf(sc0, sc1);
    float a0 = __expf(sc0 - m), a1 = __expf(sc1 - m);
    float invd = __fdividef(1.0f, a0 + a1);
    float w0 = a0 * invd * INV_SQRT_F, w1 = a1 * invd * INV_SQRT_F;
    float ov[32];
    #pragma unroll
    for (int g = 0; g < 32; g++) ov[g] = xv[g];
    #pragma unroll
    for (int sh = 0; sh < 16; sh++) {
      float w = (sh < 8 ? w0 : w1) * hvg[sh];
      #pragma unroll
      for (int g = 0; g < 32; g++) ov[g] += w * s_Bvg[sh][g];
    }
    float4* op = (float4*)&out_node[(size_t)i * 32];
    #pragma unroll
    for (int q = 0; q < 8; q++) op[q] = make_float4(ov[4*q], ov[4*q+1], ov[4*q+2], ov[4*q+3]);
  }
}

extern "C" void kernel_launch(void* const* d_in, const int* in_sizes, int n_in,
                              void* d_out, int out_size, void* d_ws, size_t ws_size,
                              hipStream_t stream)
{
  const float* pos   = (const float*)d_in[0];
  const int*   batch = (const int*)d_in[1];
  const float* xf    = (const float*)d_in[2];
  const float* bw    = (const float*)d_in[3];
  const float* Wqd   = (const float*)d_in[4];
  const float* Wk1   = (const float*)d_in[5];
  const float* Wk2   = (const float*)d_in[6];
  const float* Wv1   = (const float*)d_in[7];
  const float* Wv2   = (const float*)d_in[8];
  const float* Wqg   = (const float*)d_in[9];
  const float* Wkg1  = (const float*)d_in[10];
  const float* Wkg2  = (const float*)d_in[11];
  const float* Wvg1  = (const float*)d_in[12];
  const float* Wvg2  = (const float*)d_in[13];
  const float* Wdot  = (const float*)d_in[14];
  const float* initd = (const float*)d_in[15];
  int N = in_sizes[1];

  float* out_node  = (float*)d_out;
  float* out_dummy = out_node + (size_t)N * 32;

  // workspace layout (float offsets) — every word written before read, each call
  float*    ws      = (float*)d_ws;
  float*    ws_Tp   = ws;                        // 32*8*512 = 131072
  float*    ws_denp = ws + 131072;               // 512
  float*    ws_zf   = ws + 131584;               // 64
  int*      ws_seg  = (int*)(ws + 131648);       // 33 (+pad)
  float*    ws_Mk   = ws + 131696;               // 256
  float*    ws_WQD  = ws + 131952;               // 1024
  unsigned* ws_zp   = (unsigned*)(ws + 132976);  // ZT*64

  const int ZT = (N + 255) >> 8;

  prep_kernel<<<ZT + 2, 256, 0, stream>>>(pos, batch, Wqd, Wdot, Wqg, Wk2, initd,
                                          ws_zp, ws_seg, ws_Mk, ws_WQD, N, ZT);

  stage1_kernel<<<NBATCH * KBS1, 256, 0, stream>>>(pos, xf, bw, Wk1, Wv1, ws_seg, ws_zp,
                                                   ws_Mk, ws_Tp, ws_denp, ws_zf, N, ZT);

  stage2_kernel<<<NBATCH * KBS2, 256, 0, stream>>>(pos, xf, bw, Wkg1, Wkg2, Wvg1, Wvg2,
                                                   Wv2, initd, ws_seg, ws_Tp, ws_denp,
                                                   ws_zf, ws_WQD, out_node, out_dummy, N);
}

// Round 8
// 45.747 us; speedup vs baseline: 2.7862x; 1.3441x over previous
//
#include <hip/hip_runtime.h>

#define NBATCH 32
#define DIST 5.0f
#define EPSV 1e-6f
#define INV_SQRT_F 0.17677669529663687f   // 1/sqrt(32)
#define SC_STAGE2 1.72633492e-4f          // 32^{-5/2}
#define SL1 7     // stage-1 slices per batch -> 224 blocks (87% lane fill at cnt~1562)
#define SL2 7     // stage-2 slices per batch -> 224 blocks

__device__ __forceinline__ float silu_f(float v) { return __fdividef(v, 1.0f + __expf(-v)); }

// monotonic float <-> uint mapping for min/max via integer compares
__device__ __forceinline__ unsigned f2key(float f) {
  unsigned u = __float_as_uint(f);
  return (u & 0x80000000u) ? ~u : (u | 0x80000000u);
}
__device__ __forceinline__ float key2f(unsigned k) {
  return (k & 0x80000000u) ? __uint_as_float(k ^ 0x80000000u) : __uint_as_float(~k);
}

// ---------------- K1: z-key partials per tile + segoff + constants ----------------
extern "C" __global__ __launch_bounds__(256)
void prep_kernel(const float* __restrict__ pos, const int* __restrict__ batch,
                 const float* __restrict__ Wqd, const float* __restrict__ Wdot,
                 const float* __restrict__ Wqg, const float* __restrict__ Wk2,
                 const float* __restrict__ initd,
                 unsigned* __restrict__ ws_zp,   // [ZT][64]
                 int* __restrict__ ws_seg,       // [33]
                 float* __restrict__ ws_Mk,      // [256]
                 float* __restrict__ ws_WQD,     // [1024]
                 int N, int ZT)
{
  const int blk = blockIdx.x, tid = threadIdx.x;
  if (blk < ZT) {
    __shared__ unsigned s_pmin[NBATCH], s_pmax[NBATCH];
    if (tid < NBATCH) { s_pmin[tid] = 0xFFFFFFFFu; s_pmax[tid] = 0u; }
    __syncthreads();
    int i = (blk << 8) + tid;
    if (i < N) {
      int b = batch[i];
      unsigned k = f2key(pos[3 * (size_t)i + 2]);
      atomicMin(&s_pmin[b], k);
      atomicMax(&s_pmax[b], k);
      int bp = (i == 0) ? -1 : batch[i - 1];
      for (int bb = bp + 1; bb <= b; bb++) ws_seg[bb] = i;
      if (i == N - 1) for (int bb = b + 1; bb <= NBATCH; bb++) ws_seg[bb] = N;
    }
    __syncthreads();
    if (tid < NBATCH) {
      ws_zp[blk * 64 + tid]      = s_pmin[tid];
      ws_zp[blk * 64 + 32 + tid] = s_pmax[tid];
    }
  } else if (blk == ZT) {
    // Mk[f][h] = (1/1024) * sum_g Wk2[h,f*32+g] * c[g],  c = (initd·Wqd·invsF)·Wdot
    __shared__ float s_q[32], s_c[32];
    if (tid < 32) {
      float a = 0.f;
      #pragma unroll
      for (int f = 0; f < 32; f++) a += initd[f] * Wqd[f * 32 + tid];
      s_q[tid] = a * INV_SQRT_F;
    }
    __syncthreads();
    if (tid < 32) {
      float a = 0.f;
      #pragma unroll
      for (int f = 0; f < 32; f++) a += s_q[f] * Wdot[f * 32 + tid];
      s_c[tid] = a;
    }
    __syncthreads();
    {
      int f = tid >> 3, h = tid & 7;
      const float* w = &Wk2[h * 1024 + f * 32];
      float a = 0.f;
      #pragma unroll
      for (int g = 0; g < 32; g++) a += w[g] * s_c[g];
      ws_Mk[tid] = a * (1.0f / 1024.0f);   // tid == f*8+h
    }
  } else {
    for (int idx = tid; idx < 1024; idx += 256) {
      int f = idx >> 5, g = idx & 31;
      float a = 0.f;
      #pragma unroll
      for (int k = 0; k < 32; k++) a += Wqg[f * 32 + k] * Wdot[k * 32 + g];
      ws_WQD[idx] = a;
    }
  }
}

// ---------------- K2: stage-1 fused (z-reduce, scores, exp, T/den partial slots) ----------------
extern "C" __global__ __launch_bounds__(256)
void stage1_kernel(const float* __restrict__ pos,
                   const float* __restrict__ xfeat,
                   const float* __restrict__ bw,
                   const float* __restrict__ Wk1,
                   const float* __restrict__ Wv1,
                   const int*   __restrict__ ws_seg,
                   const unsigned* __restrict__ ws_zp,
                   const float* __restrict__ ws_Mk,
                   float* __restrict__ ws_Tp,    // [NB*SL1][512]
                   float* __restrict__ ws_denp,  // [NB*SL1][2]
                   float* __restrict__ ws_zf,    // [NB][2]
                   int N, int ZT)
{
  const int b = blockIdx.x / SL1, jb = blockIdx.x % SL1;
  const int tid = threadIdx.x;

  __shared__ unsigned s_ru[256];
  __shared__ float s_red[256];
  __shared__ float s_bw[8];
  __shared__ float s_Wa[8][8], s_Wb[8][8];
  __shared__ float s_Mk[32][8];
  __shared__ float s_exh[256][17];   // pad 17: writes 2-way (free), reads conflict-free
  __shared__ float s_xs[256][36];    // pad 36: float4-aligned rows, reads conflict-free
  __shared__ float s_Tp[4][512];

  // inline z reduction over ZT partial tiles
  unsigned kmn = 0xFFFFFFFFu, kmx = 0u;
  for (int t = tid; t < ZT; t += 256) {
    kmn = min(kmn, ws_zp[t * 64 + b]);
    kmx = max(kmx, ws_zp[t * 64 + 32 + b]);
  }
  s_ru[tid] = kmn; __syncthreads();
  for (int off = 128; off > 0; off >>= 1) { if (tid < off) s_ru[tid] = min(s_ru[tid], s_ru[tid + off]); __syncthreads(); }
  const unsigned rmn = s_ru[0]; __syncthreads();
  s_ru[tid] = kmx; __syncthreads();
  for (int off = 128; off > 0; off >>= 1) { if (tid < off) s_ru[tid] = max(s_ru[tid], s_ru[tid + off]); __syncthreads(); }
  const unsigned rmx = s_ru[0];
  const float zmin = key2f(rmn), zmax = key2f(rmx);

  if (tid < 8) s_bw[tid] = bw[tid];
  if (tid < 64) { s_Wa[tid >> 3][tid & 7] = Wk1[tid]; s_Wb[tid >> 3][tid & 7] = Wv1[tid]; }
  s_Mk[tid >> 3][tid & 7] = ws_Mk[tid];
  const int ss0 = ws_seg[b], ss1 = ws_seg[b + 1];
  __syncthreads();

  const int cnt = ss1 - ss0;
  const int per = (cnt + SL1 - 1) / SL1;
  const int lo = ss0 + jb * per;
  const int hi = min(lo + per, ss1);

  float Treg[8] = {0,0,0,0,0,0,0,0};
  float d0 = 0.f, d1 = 0.f;
  const int group = tid >> 6, gt = tid & 63, osh = gt >> 2, ofg = gt & 3;

  for (int base = lo; base < hi; base += 256) {
    int i = base + tid;
    if (i < hi) {
      float z = pos[3 * (size_t)i + 2];
      float len0 = z - zmin + DIST, len1 = zmax + DIST - z;
      float xv[32];
      const float4* xp = (const float4*)&xfeat[(size_t)i * 32];
      float4* xso = (float4*)s_xs[tid];
      #pragma unroll
      for (int q = 0; q < 8; q++) {
        float4 t = xp[q];
        xso[q] = t;
        xv[4*q] = t.x; xv[4*q+1] = t.y; xv[4*q+2] = t.z; xv[4*q+3] = t.w;
      }
      float u[8] = {0,0,0,0,0,0,0,0};
      #pragma unroll
      for (int f = 0; f < 32; f++) {
        float xf = xv[f];
        #pragma unroll
        for (int h = 0; h < 8; h++) u[h] += xf * s_Mk[f][h];
      }
      #pragma unroll
      for (int s = 0; s < 2; s++) {
        float L = s ? len1 : len0;
        float inv = __fdividef(1.0f, L + EPSV);
        float ee[8];
        #pragma unroll
        for (int j = 0; j < 8; j++) ee[j] = __sinf(s_bw[j] * L) * inv;
        float sc = 0.f;
        #pragma unroll
        for (int h = 0; h < 8; h++) {
          float a = 0.f;
          #pragma unroll
          for (int j = 0; j < 8; j++) a += ee[j] * s_Wa[j][h];
          sc += silu_f(a) * u[h];
        }
        // softmax without max-subtraction (exact ratio; clamp = overflow guard)
        float ex = __expf(fminf(fmaxf(sc, -60.f), 60.f));
        if (s) d1 += ex; else d0 += ex;
        #pragma unroll
        for (int h = 0; h < 8; h++) {
          float v = 0.f;
          #pragma unroll
          for (int j = 0; j < 8; j++) v += ee[j] * s_Wb[j][h];
          s_exh[tid][8*s + h] = ex * silu_f(v);
        }
      }
    } else {
      #pragma unroll
      for (int h = 0; h < 16; h++) s_exh[tid][h] = 0.f;
      float4* xso = (float4*)s_xs[tid];
      float4 z4 = make_float4(0.f, 0.f, 0.f, 0.f);
      #pragma unroll
      for (int q = 0; q < 8; q++) xso[q] = z4;
    }
    __syncthreads();
    const int cb = group * 64;
    for (int c = cb; c < cb + 64; c++) {
      float eh = s_exh[c][osh];
      const float4* xr4 = (const float4*)&s_xs[c][ofg * 8];
      float4 xa = xr4[0], xb = xr4[1];
      Treg[0] += eh * xa.x; Treg[1] += eh * xa.y; Treg[2] += eh * xa.z; Treg[3] += eh * xa.w;
      Treg[4] += eh * xb.x; Treg[5] += eh * xb.y; Treg[6] += eh * xb.z; Treg[7] += eh * xb.w;
    }
    __syncthreads();
  }
  #pragma unroll
  for (int k = 0; k < 8; k++) s_Tp[group][osh * 32 + ofg * 8 + k] = Treg[k];
  __syncthreads();
  const int slot = b * SL1 + jb;
  for (int idx = tid; idx < 512; idx += 256)
    ws_Tp[slot * 512 + idx] = s_Tp[0][idx] + s_Tp[1][idx] + s_Tp[2][idx] + s_Tp[3][idx];
  s_red[tid] = d0; __syncthreads();
  for (int off = 128; off > 0; off >>= 1) { if (tid < off) s_red[tid] += s_red[tid + off]; __syncthreads(); }
  if (tid == 0) ws_denp[slot * 2 + 0] = s_red[0];
  __syncthreads();
  s_red[tid] = d1; __syncthreads();
  for (int off = 128; off > 0; off >>= 1) { if (tid < off) s_red[tid] += s_red[tid + off]; __syncthreads(); }
  if (tid == 0) ws_denp[slot * 2 + 1] = s_red[0];
  if (jb == 0 && tid == 0) { ws_zf[2*b] = zmin; ws_zf[2*b+1] = zmax; }
}

// ---------------- K3: per-batch tables (redundant per block) + stage-2 output ----------------
extern "C" __global__ __launch_bounds__(256)
void stage2_kernel(const float* __restrict__ pos,
                   const float* __restrict__ xfeat,
                   const float* __restrict__ bw,
                   const float* __restrict__ Wkg1, const float* __restrict__ Wkg2,
                   const float* __restrict__ Wvg1, const float* __restrict__ Wvg2,
                   const float* __restrict__ Wv2,  const float* __restrict__ initd,
                   const int*   __restrict__ ws_seg,
                   const float* __restrict__ ws_Tp,
                   const float* __restrict__ ws_denp,
                   const float* __restrict__ ws_zf,
                   const float* __restrict__ ws_WQD,
                   float* __restrict__ out_node, float* __restrict__ out_dummy,
                   int N)
{
  const int b = blockIdx.x / SL2, jb = blockIdx.x % SL2;
  const int tid = threadIdx.x;

  __shared__ float s_bw[8];
  __shared__ float s_Wa[8][8], s_Wb[8][8];
  __shared__ float s_T[512];
  __shared__ float s_den[2];
  __shared__ float s_dp[4][2][32];
  __shared__ float s_dm[2][32];
  __shared__ float s_WQD[32][32];
  __shared__ float s_Bkg[16][32];
  __shared__ float s_Bvg[16][32];
  __shared__ float s_G[32][16];

  if (tid < 8) s_bw[tid] = bw[tid];
  if (tid < 64) { s_Wa[tid >> 3][tid & 7] = Wkg1[tid]; s_Wb[tid >> 3][tid & 7] = Wvg1[tid]; }
  if (tid < 2) {
    float d = 0.f;
    #pragma unroll
    for (int j = 0; j < SL1; j++) d += ws_denp[(b * SL1 + j) * 2 + tid];
    s_den[tid] = d;
  }
  for (int idx = tid; idx < 512; idx += 256) {
    float a = 0.f;
    #pragma unroll
    for (int j = 0; j < SL1; j++) a += ws_Tp[(b * SL1 + j) * 512 + idx];
    s_T[idx] = a;
  }
  for (int idx = tid; idx < 1024; idx += 256) s_WQD[idx >> 5][idx & 31] = ws_WQD[idx];
  const float zmin = ws_zf[2*b], zmax = ws_zf[2*b+1];
  const int ss0 = ws_seg[b], ss1 = ws_seg[b + 1];
  __syncthreads();

  // parallel dummy: thread (fq, s, g) accumulates f in [fq*8, fq*8+8)
  {
    int g = tid & 31, s = (tid >> 5) & 1, fq = tid >> 6;
    float acc = 0.f;
    #pragma unroll
    for (int h = 0; h < 8; h++) {
      #pragma unroll
      for (int f8 = 0; f8 < 8; f8++) {
        int f = fq * 8 + f8;
        acc += s_T[(8 * s + h) * 32 + f] * Wv2[h * 1024 + f * 32 + g];
      }
    }
    s_dp[fq][s][g] = acc;
  }
  __syncthreads();
  if (tid < 64) {
    int s = tid >> 5, g = tid & 31;
    float acc = s_dp[0][s][g] + s_dp[1][s][g] + s_dp[2][s][g] + s_dp[3][s][g];
    float dn = s_den[s];
    float dv = initd[g] + (dn > 0.f ? acc * INV_SQRT_F * __fdividef(1.0f, dn) : 0.f);
    s_dm[s][g] = dv;
    if (jb == 0) out_dummy[b * 64 + tid] = dv;
  }
  __syncthreads();
  for (int idx = tid; idx < 512; idx += 256) {
    int sh = idx >> 5, g = idx & 31, s = sh >> 3, h = sh & 7;
    const float* wk = &Wkg2[h * 1024 + g];
    const float* wv = &Wvg2[h * 1024 + g];
    float a = 0.f, v = 0.f;
    #pragma unroll
    for (int f = 0; f < 32; f++) { float d = s_dm[s][f]; a += d * wk[f * 32]; v += d * wv[f * 32]; }
    s_Bkg[sh][g] = a;
    s_Bvg[sh][g] = v;
  }
  __syncthreads();
  for (int idx = tid; idx < 512; idx += 256) {
    int f = idx >> 4, sh = idx & 15;
    float a = 0.f;
    #pragma unroll
    for (int g = 0; g < 32; g++) a += s_WQD[f][g] * s_Bkg[sh][g];
    s_G[f][sh] = a * SC_STAGE2;
  }
  __syncthreads();

  const int cnt = ss1 - ss0;
  const int per = (cnt + SL2 - 1) / SL2;
  const int lo = ss0 + tid + jb * per;
  const int hi = min(ss0 + (jb + 1) * per, ss1);

  for (int i = lo; i < hi; i += 256) {
    float z = pos[3 * (size_t)i + 2];
    float len0 = z - zmin + DIST, len1 = zmax + DIST - z;
    float ee[16];
    #pragma unroll
    for (int s = 0; s < 2; s++) {
      float L = s ? len1 : len0;
      float inv = __fdividef(1.0f, L + EPSV);
      #pragma unroll
      for (int j = 0; j < 8; j++) ee[8*s + j] = __sinf(s_bw[j] * L) * inv;
    }
    float hkg[16], hvg[16];
    #pragma unroll
    for (int s = 0; s < 2; s++) {
      #pragma unroll
      for (int h = 0; h < 8; h++) {
        float a = 0.f, v = 0.f;
        #pragma unroll
        for (int j = 0; j < 8; j++) { a += ee[8*s + j] * s_Wa[j][h]; v += ee[8*s + j] * s_Wb[j][h]; }
        hkg[8*s + h] = silu_f(a); hvg[8*s + h] = silu_f(v);
      }
    }
    float xv[32];
    const float4* xp = (const float4*)&xfeat[(size_t)i * 32];
    #pragma unroll
    for (int q = 0; q < 8; q++) { float4 t = xp[q]; xv[4*q] = t.x; xv[4*q+1] = t.y; xv[4*q+2] = t.z; xv[4*q+3] = t.w; }
    float ev[16] = {0,0,0,0,0,0,0,0,0,0,0,0,0,0,0,0};
    #pragma unroll
    for (int f = 0; f < 32; f++) {
      float xf = xv[f];
      #pragma unroll
      for (int sh = 0; sh < 16; sh++) ev[sh] += xf * s_G[f][sh];
    }
    float sc0 = 0.f, sc1 = 0.f;
    #pragma unroll
    for (int h = 0; h < 8; h++) { sc0 += hkg[h] * ev[h]; sc1 += hkg[8 + h] * ev[8 + h]; }
    float m = fmaxf(sc0, sc1);
    float a0 = __expf(sc0 - m), a1 = __expf(sc1 - m);
    float invd = __fdividef(1.0f, a0 + a1);
    float w0 = a0 * invd * INV_SQRT_F, w1 = a1 * invd * INV_SQRT_F;
    float wv[16];
    #pragma unroll
    for (int sh = 0; sh < 16; sh++) wv[sh] = (sh < 8 ? w0 : w1) * hvg[sh];
    float ov[32];
    #pragma unroll
    for (int g = 0; g < 32; g++) ov[g] = xv[g];
    #pragma unroll
    for (int sh = 0; sh < 16; sh++) {
      float w = wv[sh];
      #pragma unroll
      for (int g = 0; g < 32; g++) ov[g] += w * s_Bvg[sh][g];
    }
    float4* op = (float4*)&out_node[(size_t)i * 32];
    #pragma unroll
    for (int q = 0; q < 8; q++) op[q] = make_float4(ov[4*q], ov[4*q+1], ov[4*q+2], ov[4*q+3]);
  }
}

extern "C" void kernel_launch(void* const* d_in, const int* in_sizes, int n_in,
                              void* d_out, int out_size, void* d_ws, size_t ws_size,
                              hipStream_t stream)
{
  const float* pos   = (const float*)d_in[0];
  const int*   batch = (const int*)d_in[1];
  const float* xf    = (const float*)d_in[2];
  const float* bw    = (const float*)d_in[3];
  const float* Wqd   = (const float*)d_in[4];
  const float* Wk1   = (const float*)d_in[5];
  const float* Wk2   = (const float*)d_in[6];
  const float* Wv1   = (const float*)d_in[7];
  const float* Wv2   = (const float*)d_in[8];
  const float* Wqg   = (const float*)d_in[9];
  const float* Wkg1  = (const float*)d_in[10];
  const float* Wkg2  = (const float*)d_in[11];
  const float* Wvg1  = (const float*)d_in[12];
  const float* Wvg2  = (const float*)d_in[13];
  const float* Wdot  = (const float*)d_in[14];
  const float* initd = (const float*)d_in[15];
  int N = in_sizes[1];

  float* out_node  = (float*)d_out;
  float* out_dummy = out_node + (size_t)N * 32;

  // workspace layout (float offsets) — every word written before read, each call
  float*    ws      = (float*)d_ws;
  float*    ws_Tp   = ws;                        // 32*7*512 = 114688
  float*    ws_denp = ws + 114688;               // 448 (+pad)
  float*    ws_zf   = ws + 115200;               // 64
  int*      ws_seg  = (int*)(ws + 115264);       // 33 (+pad)
  float*    ws_Mk   = ws + 115312;               // 256
  float*    ws_WQD  = ws + 115568;               // 1024
  unsigned* ws_zp   = (unsigned*)(ws + 116592);  // ZT*64

  const int ZT = (N + 255) >> 8;

  prep_kernel<<<ZT + 2, 256, 0, stream>>>(pos, batch, Wqd, Wdot, Wqg, Wk2, initd,
                                          ws_zp, ws_seg, ws_Mk, ws_WQD, N, ZT);

  stage1_kernel<<<NBATCH * SL1, 256, 0, stream>>>(pos, xf, bw, Wk1, Wv1, ws_seg, ws_zp,
                                                  ws_Mk, ws_Tp, ws_denp, ws_zf, N, ZT);

  stage2_kernel<<<NBATCH * SL2, 256, 0, stream>>>(pos, xf, bw, Wkg1, Wkg2, Wvg1, Wvg2,
                                                  Wv2, initd, ws_seg, ws_Tp, ws_denp,
                                                  ws_zf, ws_WQD, out_node, out_dummy, N);
}